// Round 11
// baseline (2993.212 us; speedup 1.0000x reference)
//
#include <hip/hip_runtime.h>

// MDN-RNN persistent kernel for MI355X (gfx950).  R11: wave-autonomous publish.
// B=128, T=1000, D_IN=35, H=512, OUT=480.
// 8 batch-groups (16 batches) x 32 h-slice WGs = 256 WGs, 1/CU.
// Key change vs R10: gate wave w owns ALL 4 gates for h-cols 4w..4w+3
// (B-col m16 <-> (q=m16&3, e=m16>>2)), so MFMA -> own-segment ds_write ->
// lgkmcnt(0) -> ds_read_b128 (4 gates) -> scalar -> shfl pack -> u64 store ->
// own vmcnt(0) -> own flag is ALL wave-local: no barrier from MFMA to flag.
// 2 barriers/step (post-poll, post-h_s-write) instead of R10's 4.
// Out-GEMM: partials to pbuf[t&1]; reduce+store of row t-2 next step from
// pbuf[par^1] (ordered by the exchange barriers; no extra barrier).
// Exchange: per-wave flags (128/group), wave0-only poll with s_sleep (R4/R7
// lessons: minimal pollers, sleep backoff), bulk load 4 u64/thread.
// Lessons kept: relaxed agent atomics only (R1/R3); no traffic amplification
// (R5/R6); never trust placement (R8); reg-resident B/x (R9/R10).

#define NGRP   8
#define NSLICE 32
#define GB     16
#define HH     512
#define TT     1000
#define DIN    35
#define OUTC   480
#define ODC    15
#define HWORDS 2048      // u64 words per group h snapshot (16*512/4)

typedef __bf16 bf16x8 __attribute__((ext_vector_type(8)));
typedef float  f32x4  __attribute__((ext_vector_type(4)));
typedef unsigned short u16;
typedef unsigned int   u32;
typedef unsigned long long u64;

__device__ __forceinline__ u16 f2bf(float x) {
    u32 u = __float_as_uint(x);
    u += 0x7FFFu + ((u >> 16) & 1u);
    return (u16)(u >> 16);
}
__device__ __forceinline__ float sigf(float x) { return 1.0f / (1.0f + __expf(-x)); }
__device__ __forceinline__ float tanh_fast(float x) {
    float ax = fabsf(x);
    float e = __expf(-2.0f * ax);
    return copysignf((1.0f - e) / (1.0f + e), x);
}
__device__ __forceinline__ u32 pk2f(float a, float b) {
    return (u32)f2bf(a) | ((u32)f2bf(b) << 16);
}

union bf8u { u32 u[4]; bf16x8 v; };

#define BARRIER() do { asm volatile("" ::: "memory"); \
                       __builtin_amdgcn_s_barrier(); \
                       asm volatile("" ::: "memory"); \
                       __builtin_amdgcn_sched_barrier(0); } while (0)
#define WAIT_LGKM() do { asm volatile("s_waitcnt lgkmcnt(0)" ::: "memory"); \
                         __builtin_amdgcn_sched_barrier(0); } while (0)
#define WAIT_VM()   do { asm volatile("s_waitcnt vmcnt(0)" ::: "memory"); \
                         __builtin_amdgcn_sched_barrier(0); } while (0)

#define MFMA16(a, b, c) __builtin_amdgcn_mfma_f32_16x16x32_bf16((a), (b), (c), 0, 0, 0)

__global__ void __launch_bounds__(512, 1)
mdn_kernel(const float* __restrict__ inp, const float* __restrict__ Wk,
           const float* __restrict__ Wr,  const float* __restrict__ bg,
           const float* __restrict__ Wd,  const float* __restrict__ bd,
           float* __restrict__ out, u32* __restrict__ flags, u64* __restrict__ hbuf)
{
    __shared__ __attribute__((aligned(16))) u16  wr_s[64 * HH];   // dead after preamble
    __shared__ __attribute__((aligned(16))) u16  wk_s[64 * 64];   // dead after preamble
    __shared__ __attribute__((aligned(16))) u16  wd_s[16 * HH];   // dead after preamble
    __shared__ __attribute__((aligned(16))) u16  h_s [GB * HH];
    __shared__ __attribute__((aligned(16))) float gbuf[4 * 256];      // [w][batch][c]
    __shared__ __attribute__((aligned(16))) float pbuf[2 * 4 * 256];  // [par][kw][batch][oo]

    const int tid  = threadIdx.x;
    const int lane = tid & 63;
    const int wave = tid >> 6;
    const int g    = blockIdx.x & 7;    // batch group (XCD-affine under round-robin)
    const int s    = blockIdx.x >> 3;   // h-slice 0..31
    const int m16  = lane & 15;
    const int kq   = lane >> 4;

    // ---------------- preamble: weight staging + h_s zero ----------------
    {
        int n = tid & 63;
        int q = n >> 4, j4 = n & 15;
        int col = q * HH + s * 16 + j4;
        for (int k = tid >> 6; k < HH; k += 8)
            wr_s[n * HH + (k ^ ((n & 7) << 3))] = f2bf(Wr[(size_t)k * 2048 + col]);
        for (int k = tid >> 6; k < 64; k += 8)
            wk_s[n * 64 + (k ^ ((n & 7) << 3))] = f2bf(k < DIN ? Wk[(size_t)k * 2048 + col] : 0.0f);
    }
    {
        int n = tid & 15;
        for (int k = tid >> 4; k < HH; k += 32)
            wd_s[n * HH + (k ^ ((n & 7) << 3))] =
                f2bf(n < ODC ? Wd[(size_t)k * OUTC + s * ODC + n] : 0.0f);
    }
    for (int i = tid; i < GB * HH / 4; i += 512) ((u64*)h_s)[i] = 0ull;  // h_{-1}=0
    __syncthreads();   // one-time full sync

    // ---------------- B-fragments to registers (new gate-col mapping) ----------------
    bf16x8 bfr[18];
    if (wave < 4) {
        // wave owns hcols 4w..4w+3, all 4 gates: B-col m16 <-> (q=m16&3, e=m16>>2)
        int nloc = (m16 & 3) * 16 + 4 * wave + (m16 >> 2);   // local gate col 0..63
        #pragma unroll
        for (int ks = 0; ks < 16; ++ks) {
            int k0 = 32 * ks + 8 * kq;
            bfr[ks] = *(const bf16x8*)(&wr_s[nloc * HH + (k0 ^ ((nloc & 7) << 3))]);
        }
        #pragma unroll
        for (int i = 0; i < 2; ++i) {
            int k0 = 32 * i + 8 * kq;
            bfr[16 + i] = *(const bf16x8*)(&wk_s[nloc * 64 + (k0 ^ ((nloc & 7) << 3))]);
        }
    } else {
        int w4 = wave - 4;
        #pragma unroll
        for (int kk = 0; kk < 4; ++kk) {
            int k0 = w4 * 128 + 32 * kk + 8 * kq;
            bfr[kk] = *(const bf16x8*)(&wd_s[m16 * HH + (k0 ^ ((m16 & 7) << 3))]);
        }
    }

    // ---------------- per-lane state ----------------
    float c_reg = 0.f;
    float bi = 0.f, bff = 0.f, bgg = 0.f, boo = 0.f, bdv = 0.f;
    const int cb = lane & 15;          // gate waves: cell batch
    const int ce = lane >> 4;          // gate waves: cell hcol-in-wave (0..3)
    if (wave < 4) {
        int jj = 4 * wave + ce;        // cell hcol 0..15
        int scol = s * 16 + jj;
        bi  = bg[0 * HH + scol];
        bff = bg[1 * HH + scol];
        bgg = bg[2 * HH + scol];
        boo = bg[3 * HH + scol];
    } else {
        int oo = lane & 15;
        if (oo < ODC) bdv = bd[s * ODC + oo];
    }

    // x registers: gate lane (m16=batch, kq=k-section) owns x[m16][kq*8..+7] (+32..34 on kq==0)
    float xr[8];
    float xe0 = 0.f, xe1 = 0.f, xe2 = 0.f;
    #pragma unroll
    for (int i = 0; i < 8; ++i) xr[i] = 0.f;
    if (wave < 4) {
        const float* ip = inp + ((size_t)(g * GB + m16) * TT + 0) * DIN;
        #pragma unroll
        for (int i = 0; i < 8; ++i) xr[i] = ip[kq * 8 + i];
        if (kq == 0) { xe0 = ip[32]; xe1 = ip[33]; xe2 = ip[34]; }
    }
    __syncthreads();

    // bulk-load geometry: thread owns 16 h values (4 u64)
    const int pb = tid >> 5;      // batch row 0..15
    const int pk = tid & 31;      // k chunks pk*8 + i*256, i=0,1

    for (int t = 0; t <= TT + 1; ++t) {
        // invariant at top: h_s = h_{t-1}; xr = x_t (gate waves)
        if (wave < 4) {
            if (t < TT) {
                // ---- gate MFMA (B from regs, A from h_s/x-regs) ----
                bf8u a0, a1;
                a0.u[0] = pk2f(xr[0], xr[1]); a0.u[1] = pk2f(xr[2], xr[3]);
                a0.u[2] = pk2f(xr[4], xr[5]); a0.u[3] = pk2f(xr[6], xr[7]);
                a1.u[0] = (kq == 0) ? pk2f(xe0, xe1) : 0u;
                a1.u[1] = (kq == 0) ? pk2f(xe2, 0.f) : 0u;
                a1.u[2] = 0u; a1.u[3] = 0u;
                f32x4 acc0 = {0,0,0,0}, acc1 = {0,0,0,0};
                acc0 = MFMA16(a0.v, bfr[16], acc0);
                acc1 = MFMA16(a1.v, bfr[17], acc1);
                #pragma unroll
                for (int ks = 0; ks < 16; ks += 2) {
                    int k0 = 32 * ks + 8 * kq;
                    bf16x8 a = *(const bf16x8*)(&h_s[m16 * HH + (k0 ^ ((m16 & 7) << 3))]);
                    acc0 = MFMA16(a, bfr[ks], acc0);
                    int k1 = 32 * (ks + 1) + 8 * kq;
                    bf16x8 a2 = *(const bf16x8*)(&h_s[m16 * HH + (k1 ^ ((m16 & 7) << 3))]);
                    acc1 = MFMA16(a2, bfr[ks + 1], acc1);
                }
                // ---- same-wave D roundtrip: write [batch][c], read 4 gates ----
                #pragma unroll
                for (int j = 0; j < 4; ++j)
                    gbuf[wave * 256 + (kq * 4 + j) * 16 + m16] = acc0[j] + acc1[j];
                WAIT_LGKM();
                f32x4 gv = *(const f32x4*)(&gbuf[wave * 256 + cb * 16 + 4 * ce]);
                // ---- scalar LSTM cell (one cell per lane) ----
                float iv = gv[0] + bi, fv = gv[1] + bff;
                float gg2 = gv[2] + bgg, ov = gv[3] + boo;
                c_reg = sigf(fv) * c_reg + sigf(iv) * tanh_fast(gg2);
                float h = sigf(ov) * tanh_fast(c_reg);
                // ---- pack 4 hcols into u64 via shfl, store, drain, flag ----
                u32 hb32 = (u32)f2bf(h);
                u32 o1 = (u32)__shfl_xor((int)hb32, 16);
                u32 pair = ((ce & 1) == 0) ? (hb32 | (o1 << 16)) : (o1 | (hb32 << 16));
                u32 o2 = (u32)__shfl_xor((int)pair, 32);
                if (ce == 0) {
                    u64 w64 = (u64)pair | ((u64)o2 << 32);
                    u64* dst = hbuf + (size_t)(t & 1) * (NGRP * HWORDS) + g * HWORDS
                                  + cb * 128 + s * 4 + wave;
                    __hip_atomic_store(dst, w64, __ATOMIC_RELAXED, __HIP_MEMORY_SCOPE_AGENT);
                }
                WAIT_VM();                         // own stores at coherence point
                if (lane == 0)
                    __hip_atomic_store(&flags[(g * 128 + s * 4 + wave) * 16], (u32)(t + 1),
                                       __ATOMIC_RELAXED, __HIP_MEMORY_SCOPE_AGENT);
                // x(t+1) prefetch (rides across barriers)
                if (t + 1 < TT) {
                    const float* ip = inp + ((size_t)(g * GB + m16) * TT + (t + 1)) * DIN;
                    #pragma unroll
                    for (int i = 0; i < 8; ++i) xr[i] = ip[kq * 8 + i];
                    if (kq == 0) { xe0 = ip[32]; xe1 = ip[33]; xe2 = ip[34]; }
                }
            }
        } else {
            int w4 = wave - 4;
            if (t >= 1 && t <= TT) {
                // ---- out-GEMM partials for row t-1 (h_s = h_{t-1}) -> pbuf[t&1] ----
                f32x4 acc0 = {0,0,0,0}, acc1 = {0,0,0,0};
                #pragma unroll
                for (int kk = 0; kk < 4; kk += 2) {
                    int k0 = w4 * 128 + 32 * kk + 8 * kq;
                    bf16x8 a = *(const bf16x8*)(&h_s[m16 * HH + (k0 ^ ((m16 & 7) << 3))]);
                    acc0 = MFMA16(a, bfr[kk], acc0);
                    int k1 = w4 * 128 + 32 * (kk + 1) + 8 * kq;
                    bf16x8 a2 = *(const bf16x8*)(&h_s[m16 * HH + (k1 ^ ((m16 & 7) << 3))]);
                    acc1 = MFMA16(a2, bfr[kk + 1], acc1);
                }
                #pragma unroll
                for (int j = 0; j < 4; ++j)
                    pbuf[(t & 1) * 1024 + w4 * 256 + (kq * 4 + j) * 16 + m16] = acc0[j] + acc1[j];
            }
            if (t >= 2) {
                // ---- reduce + store row t-2 from pbuf[par^1] (barrier-ordered last step) ----
                int bb = 4 * w4 + (lane >> 4);
                int oo = lane & 15;
                int par = ((t & 1) ^ 1) * 1024;
                float v = pbuf[par + 0 * 256 + bb * 16 + oo]
                        + pbuf[par + 1 * 256 + bb * 16 + oo]
                        + pbuf[par + 2 * 256 + bb * 16 + oo]
                        + pbuf[par + 3 * 256 + bb * 16 + oo] + bdv;
                if (oo < ODC)
                    out[((size_t)(g * GB + bb) * TT + (t - 2)) * OUTC + s * ODC + oo] = v;
            }
        }

        // ================= exchange =================
        if (t < TT) {
            // detect: wave0 polls 128 per-wave flags (2/lane, sleep backoff)
            if (wave == 0) {
                const u32* f0 = flags + (g * 128 + lane) * 16;
                const u32* f1 = flags + (g * 128 + 64 + lane) * 16;
                const u32 tgt = (u32)(t + 1);
                int spins = 0;
                while (true) {
                    u32 a = __hip_atomic_load(f0, __ATOMIC_RELAXED, __HIP_MEMORY_SCOPE_AGENT);
                    u32 b = __hip_atomic_load(f1, __ATOMIC_RELAXED, __HIP_MEMORY_SCOPE_AGENT);
                    if (__all((int)(a >= tgt && b >= tgt))) break;
                    __builtin_amdgcn_s_sleep(1);
                    if (++spins > (1 << 18)) break;        // bounded bail-out: no hangs
                }
            }
            BARRIER();                                     // #1 (post-poll)
            // bulk load h_t (4 u64/thread) + swizzled ds_write into h_s
            {
                const u64* bp = hbuf + (size_t)(t & 1) * (NGRP * HWORDS) + g * HWORDS;
                #pragma unroll
                for (int i = 0; i < 2; ++i) {
                    int widx = pb * 128 + pk * 2 + i * 64;
                    u64 vlo = __hip_atomic_load(bp + widx,     __ATOMIC_RELAXED, __HIP_MEMORY_SCOPE_AGENT);
                    u64 vhi = __hip_atomic_load(bp + widx + 1, __ATOMIC_RELAXED, __HIP_MEMORY_SCOPE_AGENT);
                    int k  = pk * 8 + i * 256;
                    int sk = k ^ ((pb & 7) << 3);          // XOR moves 8-blocks whole
                    *(u64*)(&h_s[pb * HH + sk])     = vlo;
                    *(u64*)(&h_s[pb * HH + sk + 4]) = vhi;
                }
            }
            WAIT_LGKM(); BARRIER();                        // #2 (h_s ready)
        } else {
            // tail steps (t = TT, TT+1): order pbuf handoff for the delayed reduce
            WAIT_LGKM(); BARRIER();
        }
    }
}

extern "C" void kernel_launch(void* const* d_in, const int* in_sizes, int n_in,
                              void* d_out, int out_size, void* d_ws, size_t ws_size,
                              hipStream_t stream) {
    const float* inp = (const float*)d_in[0];
    const float* Wk  = (const float*)d_in[1];
    const float* Wr  = (const float*)d_in[2];
    const float* bg  = (const float*)d_in[3];
    const float* Wd  = (const float*)d_in[4];
    const float* bd  = (const float*)d_in[5];
    float* out = (float*)d_out;

    // ws: [0,65536): flags, 8 groups x 128 per-wave flags x 16 u32 (64B apart)
    //     [65536, 65536+262144): h double buffers, 2 x 8 x 2048 u64 (flag-gated)
    char* ws = (char*)d_ws;
    u32* flags = (u32*)ws;
    u64* hbuf  = (u64*)(ws + 65536);
    hipMemsetAsync(d_ws, 0, 65536, stream);

    hipLaunchKernelGGL(mdn_kernel, dim3(NGRP * NSLICE), dim3(512), 0, stream,
                       inp, Wk, Wr, bg, Wd, bd, out, flags, hbuf);
}

// Round 12
// 2940.962 us; speedup vs baseline: 1.0178x; 1.0178x over previous
//
#include <hip/hip_runtime.h>

// MDN-RNN persistent kernel for MI355X (gfx950).  R12: same-wave gates (R11) +
// full-line slice-major publish + last-publisher LDS-counter flag.
// B=128, T=1000, D_IN=35, H=512, OUT=480.
// 8 batch-groups (16 batches) x 32 h-slice WGs = 256 WGs, 1/CU.
// Gate wave w owns ALL 4 gates for h-cols 4w..4w+3 (R11 mapping, verified):
// MFMA -> own gbuf seg -> lgkm -> read 4 gates -> cell -> shfl pack ->
// u64 store (hbuf[s][w][b]: 16 consecutive u64 = 128B = 2 FULL lines/wave,
// no partial-line HBM write amplification, fixes R11's 2x WRITE_SIZE) ->
// own vmcnt(0) -> monotonic LDS pub-counter; LAST wave (old==4t+3) stores the
// single WG flag. No WG barrier anywhere on the publish path.
// Poll: wave0, 32 flags/group, s_sleep(1) (R4/R10-proven). Bulk load: thread t
// loads words {t, t+512, t+1024, t+1536} (unit-stride, fully coalesced).
// Out waves: delayed reduce row t-2 + MFMA row t-1 (R11-verified), barrier-
// ordered double pbuf. 2 barriers/step.
// Lessons: R1/R3 no cache-wide fences; R5/R6 no traffic amplification; R7
// minimal pollers; R8 never trust placement; R9/R10 reg-resident B/x, typed
// waits; R11 partial-line scattered publishes double HBM writes.

#define NGRP   8
#define NSLICE 32
#define GB     16
#define HH     512
#define TT     1000
#define DIN    35
#define OUTC   480
#define ODC    15
#define HWORDS 2048      // u64 words per group h snapshot (16*512/4)

typedef __bf16 bf16x8 __attribute__((ext_vector_type(8)));
typedef float  f32x4  __attribute__((ext_vector_type(4)));
typedef unsigned short u16;
typedef unsigned int   u32;
typedef unsigned long long u64;

__device__ __forceinline__ u16 f2bf(float x) {
    u32 u = __float_as_uint(x);
    u += 0x7FFFu + ((u >> 16) & 1u);
    return (u16)(u >> 16);
}
__device__ __forceinline__ float sigf(float x) { return 1.0f / (1.0f + __expf(-x)); }
__device__ __forceinline__ float tanh_fast(float x) {
    float ax = fabsf(x);
    float e = __expf(-2.0f * ax);
    return copysignf((1.0f - e) / (1.0f + e), x);
}
__device__ __forceinline__ u32 pk2f(float a, float b) {
    return (u32)f2bf(a) | ((u32)f2bf(b) << 16);
}

union bf8u { u32 u[4]; bf16x8 v; };

#define BARRIER() do { asm volatile("" ::: "memory"); \
                       __builtin_amdgcn_s_barrier(); \
                       asm volatile("" ::: "memory"); \
                       __builtin_amdgcn_sched_barrier(0); } while (0)
#define WAIT_LGKM() do { asm volatile("s_waitcnt lgkmcnt(0)" ::: "memory"); \
                         __builtin_amdgcn_sched_barrier(0); } while (0)
#define WAIT_VM()   do { asm volatile("s_waitcnt vmcnt(0)" ::: "memory"); \
                         __builtin_amdgcn_sched_barrier(0); } while (0)

#define MFMA16(a, b, c) __builtin_amdgcn_mfma_f32_16x16x32_bf16((a), (b), (c), 0, 0, 0)

__global__ void __launch_bounds__(512, 1)
mdn_kernel(const float* __restrict__ inp, const float* __restrict__ Wk,
           const float* __restrict__ Wr,  const float* __restrict__ bg,
           const float* __restrict__ Wd,  const float* __restrict__ bd,
           float* __restrict__ out, u32* __restrict__ flags, u64* __restrict__ hbuf)
{
    __shared__ __attribute__((aligned(16))) u16  wr_s[64 * HH];   // dead after preamble
    __shared__ __attribute__((aligned(16))) u16  wk_s[64 * 64];   // dead after preamble
    __shared__ __attribute__((aligned(16))) u16  wd_s[16 * HH];   // dead after preamble
    __shared__ __attribute__((aligned(16))) u16  h_s [GB * HH];
    __shared__ __attribute__((aligned(16))) float gbuf[4 * 256];      // [w][batch][c]
    __shared__ __attribute__((aligned(16))) float pbuf[2 * 4 * 256];  // [par][kw][batch][oo]
    __shared__ int pubcnt;                                            // monotonic

    const int tid  = threadIdx.x;
    const int lane = tid & 63;
    const int wave = tid >> 6;
    const int g    = blockIdx.x & 7;    // batch group (XCD-affine under round-robin)
    const int s    = blockIdx.x >> 3;   // h-slice 0..31
    const int m16  = lane & 15;
    const int kq   = lane >> 4;

    // ---------------- preamble: weight staging + h_s zero ----------------
    {
        int n = tid & 63;
        int q = n >> 4, j4 = n & 15;
        int col = q * HH + s * 16 + j4;
        for (int k = tid >> 6; k < HH; k += 8)
            wr_s[n * HH + (k ^ ((n & 7) << 3))] = f2bf(Wr[(size_t)k * 2048 + col]);
        for (int k = tid >> 6; k < 64; k += 8)
            wk_s[n * 64 + (k ^ ((n & 7) << 3))] = f2bf(k < DIN ? Wk[(size_t)k * 2048 + col] : 0.0f);
    }
    {
        int n = tid & 15;
        for (int k = tid >> 4; k < HH; k += 32)
            wd_s[n * HH + (k ^ ((n & 7) << 3))] =
                f2bf(n < ODC ? Wd[(size_t)k * OUTC + s * ODC + n] : 0.0f);
    }
    for (int i = tid; i < GB * HH / 4; i += 512) ((u64*)h_s)[i] = 0ull;  // h_{-1}=0
    if (tid == 0) pubcnt = 0;
    __syncthreads();   // one-time full sync

    // ---------------- B-fragments to registers (R11 gate-col mapping) ----------------
    bf16x8 bfr[18];
    if (wave < 4) {
        // wave owns hcols 4w..4w+3, all 4 gates: B-col m16 <-> (q=m16&3, e=m16>>2)
        int nloc = (m16 & 3) * 16 + 4 * wave + (m16 >> 2);   // local gate col 0..63
        #pragma unroll
        for (int ks = 0; ks < 16; ++ks) {
            int k0 = 32 * ks + 8 * kq;
            bfr[ks] = *(const bf16x8*)(&wr_s[nloc * HH + (k0 ^ ((nloc & 7) << 3))]);
        }
        #pragma unroll
        for (int i = 0; i < 2; ++i) {
            int k0 = 32 * i + 8 * kq;
            bfr[16 + i] = *(const bf16x8*)(&wk_s[nloc * 64 + (k0 ^ ((nloc & 7) << 3))]);
        }
    } else {
        int w4 = wave - 4;
        #pragma unroll
        for (int kk = 0; kk < 4; ++kk) {
            int k0 = w4 * 128 + 32 * kk + 8 * kq;
            bfr[kk] = *(const bf16x8*)(&wd_s[m16 * HH + (k0 ^ ((m16 & 7) << 3))]);
        }
    }

    // ---------------- per-lane state ----------------
    float c_reg = 0.f;
    float bi = 0.f, bff = 0.f, bgg = 0.f, boo = 0.f, bdv = 0.f;
    const int cb = lane & 15;          // gate waves: cell batch
    const int ce = lane >> 4;          // gate waves: cell hcol-in-wave (0..3)
    if (wave < 4) {
        int jj = 4 * wave + ce;        // cell hcol 0..15
        int scol = s * 16 + jj;
        bi  = bg[0 * HH + scol];
        bff = bg[1 * HH + scol];
        bgg = bg[2 * HH + scol];
        boo = bg[3 * HH + scol];
    } else {
        int oo = lane & 15;
        if (oo < ODC) bdv = bd[s * ODC + oo];
    }

    // x registers: gate lane (m16=batch, kq=k-section) owns x[m16][kq*8..+7] (+32..34, kq==0)
    float xr[8];
    float xe0 = 0.f, xe1 = 0.f, xe2 = 0.f;
    #pragma unroll
    for (int i = 0; i < 8; ++i) xr[i] = 0.f;
    if (wave < 4) {
        const float* ip = inp + ((size_t)(g * GB + m16) * TT + 0) * DIN;
        #pragma unroll
        for (int i = 0; i < 8; ++i) xr[i] = ip[kq * 8 + i];
        if (kq == 0) { xe0 = ip[32]; xe1 = ip[33]; xe2 = ip[34]; }
    }
    __syncthreads();

    for (int t = 0; t <= TT + 1; ++t) {
        // invariant at top: h_s = h_{t-1}; xr = x_t (gate waves)
        if (wave < 4) {
            if (t < TT) {
                // ---- gate MFMA ----
                bf8u a0, a1;
                a0.u[0] = pk2f(xr[0], xr[1]); a0.u[1] = pk2f(xr[2], xr[3]);
                a0.u[2] = pk2f(xr[4], xr[5]); a0.u[3] = pk2f(xr[6], xr[7]);
                a1.u[0] = (kq == 0) ? pk2f(xe0, xe1) : 0u;
                a1.u[1] = (kq == 0) ? pk2f(xe2, 0.f) : 0u;
                a1.u[2] = 0u; a1.u[3] = 0u;
                f32x4 acc0 = {0,0,0,0}, acc1 = {0,0,0,0};
                acc0 = MFMA16(a0.v, bfr[16], acc0);
                acc1 = MFMA16(a1.v, bfr[17], acc1);
                #pragma unroll
                for (int ks = 0; ks < 16; ks += 2) {
                    int k0 = 32 * ks + 8 * kq;
                    bf16x8 a = *(const bf16x8*)(&h_s[m16 * HH + (k0 ^ ((m16 & 7) << 3))]);
                    acc0 = MFMA16(a, bfr[ks], acc0);
                    int k1 = 32 * (ks + 1) + 8 * kq;
                    bf16x8 a2 = *(const bf16x8*)(&h_s[m16 * HH + (k1 ^ ((m16 & 7) << 3))]);
                    acc1 = MFMA16(a2, bfr[ks + 1], acc1);
                }
                // ---- same-wave D roundtrip ----
                #pragma unroll
                for (int j = 0; j < 4; ++j)
                    gbuf[wave * 256 + (kq * 4 + j) * 16 + m16] = acc0[j] + acc1[j];
                WAIT_LGKM();
                f32x4 gv = *(const f32x4*)(&gbuf[wave * 256 + cb * 16 + 4 * ce]);
                // ---- scalar LSTM cell ----
                float iv = gv[0] + bi, fv = gv[1] + bff;
                float gg2 = gv[2] + bgg, ov = gv[3] + boo;
                c_reg = sigf(fv) * c_reg + sigf(iv) * tanh_fast(gg2);
                float h = sigf(ov) * tanh_fast(c_reg);
                // ---- pack 4 hcols, full-line store at hbuf[s][wave][cb] ----
                u32 hb32 = (u32)f2bf(h);
                u32 o1 = (u32)__shfl_xor((int)hb32, 16);
                u32 pair = ((ce & 1) == 0) ? (hb32 | (o1 << 16)) : (o1 | (hb32 << 16));
                u32 o2 = (u32)__shfl_xor((int)pair, 32);
                if (ce == 0) {
                    u64 w64 = (u64)pair | ((u64)o2 << 32);   // hcols 4w..4w+3
                    u64* dst = hbuf + (size_t)(t & 1) * (NGRP * HWORDS) + g * HWORDS
                                  + s * 64 + wave * 16 + cb;  // 16 consecutive u64/wave
                    __hip_atomic_store(dst, w64, __ATOMIC_RELAXED, __HIP_MEMORY_SCOPE_AGENT);
                }
                WAIT_VM();                          // own h stores at coherence point
                // monotonic LDS counter: last publisher wave stores the WG flag
                if (lane == 0) {
                    int old = atomicAdd(&pubcnt, 1);
                    if (old == 4 * t + 3)
                        __hip_atomic_store(&flags[(g * NSLICE + s) * 16], (u32)(t + 1),
                                           __ATOMIC_RELAXED, __HIP_MEMORY_SCOPE_AGENT);
                }
                // x(t+1) prefetch (after drain: rides across barriers)
                if (t + 1 < TT) {
                    const float* ip = inp + ((size_t)(g * GB + m16) * TT + (t + 1)) * DIN;
                    #pragma unroll
                    for (int i = 0; i < 8; ++i) xr[i] = ip[kq * 8 + i];
                    if (kq == 0) { xe0 = ip[32]; xe1 = ip[33]; xe2 = ip[34]; }
                }
            }
        } else {
            int w4 = wave - 4;
            if (t >= 2) {
                // ---- reduce + store row t-2 from pbuf[prev] (barrier-ordered) ----
                int bb = 4 * w4 + (lane >> 4);
                int oo = lane & 15;
                int par = ((t & 1) ^ 1) * 1024;
                float v = pbuf[par + 0 * 256 + bb * 16 + oo]
                        + pbuf[par + 1 * 256 + bb * 16 + oo]
                        + pbuf[par + 2 * 256 + bb * 16 + oo]
                        + pbuf[par + 3 * 256 + bb * 16 + oo] + bdv;
                if (oo < ODC)
                    out[((size_t)(g * GB + bb) * TT + (t - 2)) * OUTC + s * ODC + oo] = v;
            }
            if (t >= 1 && t <= TT) {
                // ---- out-GEMM partials row t-1 (h_s = h_{t-1}) -> pbuf[t&1] ----
                f32x4 acc0 = {0,0,0,0}, acc1 = {0,0,0,0};
                #pragma unroll
                for (int kk = 0; kk < 4; kk += 2) {
                    int k0 = w4 * 128 + 32 * kk + 8 * kq;
                    bf16x8 a = *(const bf16x8*)(&h_s[m16 * HH + (k0 ^ ((m16 & 7) << 3))]);
                    acc0 = MFMA16(a, bfr[kk], acc0);
                    int k1 = w4 * 128 + 32 * (kk + 1) + 8 * kq;
                    bf16x8 a2 = *(const bf16x8*)(&h_s[m16 * HH + (k1 ^ ((m16 & 7) << 3))]);
                    acc1 = MFMA16(a2, bfr[kk + 1], acc1);
                }
                #pragma unroll
                for (int j = 0; j < 4; ++j)
                    pbuf[(t & 1) * 1024 + w4 * 256 + (kq * 4 + j) * 16 + m16] = acc0[j] + acc1[j];
            }
        }

        // ================= exchange =================
        if (t < TT) {
            // detect: wave0 polls 32 WG flags (R4/R10-proven)
            if (wave == 0) {
                const u32* fp = flags + (g * NSLICE + (lane & 31)) * 16;
                const u32 tgt = (u32)(t + 1);
                int spins = 0;
                while (true) {
                    u32 v = __hip_atomic_load(fp, __ATOMIC_RELAXED, __HIP_MEMORY_SCOPE_AGENT);
                    if (__all((int)(v >= tgt))) break;
                    __builtin_amdgcn_s_sleep(1);
                    if (++spins > (1 << 20)) break;        // bounded bail-out: no hangs
                }
            }
            BARRIER();                                     // #1 (post-poll)
            // bulk load h_t: thread t loads words {t, t+512, t+1024, t+1536}
            // (unit-stride across lanes); word L -> slice L>>6, prod-wave (L>>4)&3,
            // batch L&15 -> h cols (L>>6)*16 + 4*((L>>4)&3) .. +3
            {
                const u64* bp = hbuf + (size_t)(t & 1) * (NGRP * HWORDS) + g * HWORDS;
                #pragma unroll
                for (int i = 0; i < 4; ++i) {
                    int L = tid + i * 512;
                    u64 v = __hip_atomic_load(bp + L, __ATOMIC_RELAXED, __HIP_MEMORY_SCOPE_AGENT);
                    int b    = L & 15;
                    int kcol = (L >> 6) * 16 + 4 * ((L >> 4) & 3);
                    *(u64*)(&h_s[b * HH + (kcol ^ ((b & 7) << 3))]) = v;
                }
            }
            WAIT_LGKM(); BARRIER();                        // #2 (h_s ready)
        } else {
            // tail steps (t = TT, TT+1): order pbuf handoff for delayed reduce
            WAIT_LGKM(); BARRIER();
        }
    }
}

extern "C" void kernel_launch(void* const* d_in, const int* in_sizes, int n_in,
                              void* d_out, int out_size, void* d_ws, size_t ws_size,
                              hipStream_t stream) {
    const float* inp = (const float*)d_in[0];
    const float* Wk  = (const float*)d_in[1];
    const float* Wr  = (const float*)d_in[2];
    const float* bg  = (const float*)d_in[3];
    const float* Wd  = (const float*)d_in[4];
    const float* bd  = (const float*)d_in[5];
    float* out = (float*)d_out;

    // ws: [0,16384): flags, 8 groups x 32 slices x 16 u32 (64B apart, zeroed)
    //     [16384, 16384+262144): h double buffers, 2 x 8 x 2048 u64 (flag-gated)
    char* ws = (char*)d_ws;
    u32* flags = (u32*)ws;
    u64* hbuf  = (u64*)(ws + 16384);
    hipMemsetAsync(d_ws, 0, 16384, stream);

    hipLaunchKernelGGL(mdn_kernel, dim3(NGRP * NSLICE), dim3(512), 0, stream,
                       inp, Wk, Wr, bg, Wd, bd, out, flags, hbuf);
}